// Round 6
// baseline (563.559 us; speedup 1.0000x reference)
//
#include <hip/hip_runtime.h>
#include <math.h>

#define N_NODES 4096
#define WORDS   64
#define HID     256
#define VOCAB   50257
#define NCLASS  4
#define N_LEAF  2048
#define RNN_BLOCKS 256     // 1 block/CU -> all resident, spin-wait safe
#define POISON 0x7FFF7FFFu // half2 (NaN,NaN); finite packed rows never match

typedef _Float16 half2_t __attribute__((ext_vector_type(2)));

__device__ __forceinline__ float dot2f(half2_t a, half2_t b, float c) {
#if __has_builtin(__builtin_amdgcn_fdot2)
  return __builtin_amdgcn_fdot2(a, b, c, false);   // v_dot2_f32_f16
#else
  return c + (float)a.x * (float)b.x + (float)a.y * (float)b.y;
#endif
}

__device__ __forceinline__ half2_t f2h2(float f) {
  union { float f; half2_t h; } u; u.f = f; return u.h;
}

__device__ __forceinline__ float fast_rcp(float x) { return __builtin_amdgcn_rcpf(x); }
__device__ __forceinline__ float fast_sigmoid(float x) {        // rcp-based, no IEEE div seq
  return fast_rcp(1.f + __expf(-x));
}
__device__ __forceinline__ float fast_tanh(float x) {           // 1 - 2/(e^{2x}+1); saturates to +-1
  return 1.f - 2.f * fast_rcp(1.f + __expf(2.f * x));
}
__device__ __forceinline__ half2_t pkrtz(float a, float b) {    // single v_cvt_pkrtz_f16_f32
#if __has_builtin(__builtin_amdgcn_cvt_pkrtz)
  return __builtin_bit_cast(half2_t, __builtin_amdgcn_cvt_pkrtz(a, b));
#else
  half2_t v; v.x = (_Float16)a; v.y = (_Float16)b; return v;
#endif
}

// ---------------------------------------------------------------- poison Hpk (the handoff medium)
__global__ void poison_hpk_kernel(unsigned* __restrict__ HpkU) {
  int i = blockIdx.x * blockDim.x + threadIdx.x;
  if (i < N_NODES * (HID / 2)) HpkU[i] = POISON;
}

// ---------------------------------------------------------------- E (HID,VOCAB) f32 -> ETh (VOCAB,HID) f16
__global__ void transpose_f16_kernel(const float* __restrict__ src, _Float16* __restrict__ dst,
                                     int R, int C) {
  __shared__ float tile[32][33];
  int c0 = blockIdx.x * 32, r0 = blockIdx.y * 32;
  int tx = threadIdx.x, ty = threadIdx.y;
#pragma unroll
  for (int j = 0; j < 32; j += 8) {
    int c = c0 + tx, r = r0 + ty + j;
    if (c < C) tile[ty + j][tx] = src[(size_t)r * C + c];
  }
  __syncthreads();
#pragma unroll
  for (int j = 0; j < 32; j += 8) {
    int c = c0 + ty + j, r = r0 + tx;
    if (c < C) dst[(size_t)c * R + r] = (_Float16)tile[tx][ty + j];
  }
}

// ---------------------------------------------------------------- pack U and W -> half2
// Layout: packed[m][kp][h] = (M[h][2kp], M[h][2kp+1]), linear idx (m*4+s)*8192 + j*256 + h
// with kp = s*32+j. m = 0..5 -> Uz,Ur,Uh,Wz,Wr,Wh.
__global__ void __launch_bounds__(256) pack_u_kernel(
    const float* __restrict__ Uz, const float* __restrict__ Ur, const float* __restrict__ Uh,
    const float* __restrict__ Wz, const float* __restrict__ Wr, const float* __restrict__ Wh,
    half2_t* __restrict__ Upk) {
  __shared__ float tile[64][259];
  int m = blockIdx.x >> 2, g = blockIdx.x & 3;
  const float* U = m == 0 ? Uz : (m == 1 ? Ur : (m == 2 ? Uh : (m == 3 ? Wz : (m == 4 ? Wr : Wh))));
  int t = threadIdx.x;
  for (int r = 0; r < 64; ++r) tile[r][t] = U[(size_t)(g * 64 + r) * 256 + t];
  __syncthreads();
#pragma unroll
  for (int it = 0; it < 32; ++it) {
    int e = it * 256 + t;
    int hl = e & 63, kj = e >> 6, s = kj >> 5, j = kj & 31;
    half2_t v;
    v.x = (_Float16)tile[hl][s * 64 + 2 * j];
    v.y = (_Float16)tile[hl][s * 64 + 2 * j + 1];
    Upk[(size_t)(m * 4 + s) * 8192 + j * 256 + (g * 64 + hl)] = v;
  }
}

// ---------------------------------------------------------------- fused gather + 3-gate GEMV
// R15 (kept): one block per 4 nodes, 256 threads. Gather X rows -> f16 LDS, then
// A_m[i][n] = sum_kp dot2(Wpk[m][kp][n], Xh[i][kp]) with 4-node W reuse.
__global__ void __launch_bounds__(256) gather_gemv_kernel(
    const int* __restrict__ tree, const half2_t* __restrict__ ETh2,
    const half2_t* __restrict__ Upk,
    float* __restrict__ Az, float* __restrict__ Ar, float* __restrict__ Ah,
    float* __restrict__ H, half2_t* __restrict__ Hpk) {
  const int t  = threadIdx.x;
  const int i0 = blockIdx.x * 4;
  __shared__ int     vsf[4 * WORDS];       // 4 nodes' word ids (contiguous in tree)
  __shared__ float2  ps[256];              // gather partial sums
  __shared__ half2_t Xh[4][HID / 2];       // 4 nodes' X rows, f16 pairs

  vsf[t] = tree[(size_t)i0 * WORDS + t];   // 4*64 = 256 words, coalesced
  __syncthreads();

  const int c    = t & 127;                // half2 column
  const int half = t >> 7;                 // word-half
#pragma unroll
  for (int n = 0; n < 4; ++n) {
    float ax = 0.f, ay = 0.f;
    const int base = n * WORDS + half * 32;
#pragma unroll 8
    for (int w = 0; w < 32; ++w) {
      half2_t e = ETh2[(size_t)vsf[base + w] * (HID / 2) + c];
      ax += (float)e.x;
      ay += (float)e.y;
    }
    ps[t].x = ax; ps[t].y = ay;
    __syncthreads();
    if (t < 128) {
      float xx = ps[t].x + ps[t + 128].x;
      float yy = ps[t].y + ps[t + 128].y;
      half2_t hv; hv.x = (_Float16)xx; hv.y = (_Float16)yy;   // RNE casts (match old gather)
      Xh[n][t] = hv;
      if (i0 + n == 0) {                   // node 0: seed fp32 H row + packed Hpk row
        float2 v2; v2.x = xx; v2.y = yy;
        ((float2*)H)[t] = v2;
        Hpk[t] = hv;
      }
    }
    __syncthreads();                       // ps reusable; Xh[n] visible to all
  }

  // ---- GEMV: 3 gates x 4 nodes, output neuron = t
  float acc[3][4];
#pragma unroll
  for (int m = 0; m < 3; ++m)
#pragma unroll
    for (int n = 0; n < 4; ++n) acc[m][n] = 0.f;

  const half2_t* wb = Upk + (size_t)12 * 8192 + t;   // m=3 (Wz) base, +32768 per gate
#pragma unroll 8
  for (int kp = 0; kp < 128; ++kp) {
    half2_t w0 = wb[kp * 256];
    half2_t w1 = wb[kp * 256 + 32768];
    half2_t w2 = wb[kp * 256 + 65536];
    half2_t x0 = Xh[0][kp], x1 = Xh[1][kp], x2 = Xh[2][kp], x3 = Xh[3][kp];  // LDS broadcast
    acc[0][0] = dot2f(w0, x0, acc[0][0]); acc[0][1] = dot2f(w0, x1, acc[0][1]);
    acc[0][2] = dot2f(w0, x2, acc[0][2]); acc[0][3] = dot2f(w0, x3, acc[0][3]);
    acc[1][0] = dot2f(w1, x0, acc[1][0]); acc[1][1] = dot2f(w1, x1, acc[1][1]);
    acc[1][2] = dot2f(w1, x2, acc[1][2]); acc[1][3] = dot2f(w1, x3, acc[1][3]);
    acc[2][0] = dot2f(w2, x0, acc[2][0]); acc[2][1] = dot2f(w2, x1, acc[2][1]);
    acc[2][2] = dot2f(w2, x2, acc[2][2]); acc[2][3] = dot2f(w2, x3, acc[2][3]);
  }
#pragma unroll
  for (int n = 0; n < 4; ++n) {
    Az[(size_t)(i0 + n) * HID + t] = acc[0][n];
    Ar[(size_t)(i0 + n) * HID + t] = acc[1][n];
    Ah[(size_t)(i0 + n) * HID + t] = acc[2][n];
  }
}

// ---------------------------------------------------------------- persistent wavefront GRU scan (block-cyclic)
// R16: 3-role re-shard for TRUE register residency of U.
// Evidence: R0/R15 declare 192 half2 of per-thread U but rocprof shows VGPR_Count=120 —
// at 2 waves/EU (256-reg budget) demand ~272 means the compiler AGPR-stashed / L2-reloaded
// U on every node step (a hidden ~30-60% per-step tax; why issue-count models mispredicted).
// Fix: 768 threads, 12 waves, 3 waves/EU (pool 512/3 = 170 regs): each thread holds ONE
// full U row (128 half2) + ~40 working regs -> fits arch VGPRs, no stash, no reload.
//   Z (tid<256):    Uz row; phase1 dot -> g -> gv[h]
//   R (256..511):   Ur row; phase1 dot -> r -> r*ph packed -> rhp
//   C (512..767):   Uh row; phase2 full-K dot over rhp -> c, epilogue, stores
// Issue totals identical to R0 (phase1: 2 waves/SIMD x 128 dot2; phase2: 1 wave x 128) ->
// this round isolates the residency tax. Also: part[]+B2 eliminated (C holds full-K Uh;
// the R13 goal WITHOUT its serialized z/r chain), and Z polls the next node's parent
// post-B1 overlapped with C's phase2 (early by only ~1 phase, avoiding R13's long-window
// hot-line polling).
// Race audit: php reads all end by B1 (Z,R dot it; C reads only phv just after B0) -> Z's
// post-B1 php refill is safe; gv written by Z pre-B1(t), read by C post-B1(t), next write
// post-B0(t+1) which waits for C; rhp written pre-B1(t), read by C before it reaches
// B0(t+1). All 768 threads hit B0/B1 unconditionally each iteration; liveness grounded at
// node 0 (seeded by gather). Escape hatch 1<<22 -> poisoned diagnosable output, no hang.
__global__ void
__attribute__((amdgpu_flat_work_group_size(768, 768), amdgpu_waves_per_eu(3, 3)))
rnn_kernel(
    const float* __restrict__ Az, const float* __restrict__ Ar, const float* __restrict__ Ah,
    const half2_t* __restrict__ Upk,
    const float* __restrict__ bz, const float* __restrict__ br, const float* __restrict__ bh,
    const int* __restrict__ edge, float* __restrict__ H, unsigned* HpkU) {
  const int tid  = threadIdx.x;
  const int role = tid >> 8;           // 0=Z (Uz,g)  1=R (Ur,r)  2=C (Uh,epilogue)
  const int h    = tid & (HID - 1);
  __shared__ half2_t php[HID / 2];
  __shared__ half2_t rhp[HID / 2];
  __shared__ float   gv[HID];

  // one-time U row load (full unroll -> SSA -> arch register file; fits at 3 waves/EU)
  half2_t u[128];
  {
    const half2_t* ub = Upk + (size_t)(role * 4) * 8192 + h;   // m = role: Uz/Ur/Uh
#pragma unroll
    for (int j = 0; j < 128; ++j)
      u[j] = ub[(j >> 5) * 8192 + (j & 31) * 256];
  }
  const float  bias = role == 0 ? bz[h] : (role == 1 ? br[h] : bh[h]);
  const float* Aptr = role == 0 ? Az : (role == 1 ? Ar : Ah);

  const int istart = blockIdx.x == 0 ? RNN_BLOCKS : blockIdx.x;  // node 0 pre-seeded by gather

  // prologue: A-row for istart; pollers (tid<128) fetch parent(istart) into php
  float a = Aptr[(size_t)istart * HID + h];
  if (tid < HID / 2) {
    const int p = edge[2 * istart];    // parent, p < istart
    unsigned v = __hip_atomic_load(&HpkU[(size_t)p * (HID / 2) + tid],
                                   __ATOMIC_RELAXED, __HIP_MEMORY_SCOPE_AGENT);
    long spin = 0;
    while (v == POISON) {
      if (++spin > (1L << 22)) break;  // escape hatch (should never trigger)
      v = __hip_atomic_load(&HpkU[(size_t)p * (HID / 2) + tid],
                            __ATOMIC_RELAXED, __HIP_MEMORY_SCOPE_AGENT);
    }
    php[tid] = __builtin_bit_cast(half2_t, v);
  }

  for (int i = istart; i < N_NODES; i += RNN_BLOCKS) {
    __syncthreads();   // B0: parent row resident in php
    half2_t ph2 = php[h >> 1];
    const float phv = (float)((h & 1) ? ph2.y : ph2.x);
    const int inext = i + RNN_BLOCKS;

    if (role < 2) {
      // phase 1: Z and R full-K dots against packed parent row (broadcast LDS reads)
      const float4* vq = (const float4*)php;
      float ac0 = 0.f, ac1 = 0.f, ac2 = 0.f, ac3 = 0.f;
#pragma unroll
      for (int q = 0; q < 32; ++q) {
        float4 blk = vq[q];
        ac0 = dot2f(u[4 * q + 0], f2h2(blk.x), ac0);
        ac1 = dot2f(u[4 * q + 1], f2h2(blk.y), ac1);
        ac2 = dot2f(u[4 * q + 2], f2h2(blk.z), ac2);
        ac3 = dot2f(u[4 * q + 3], f2h2(blk.w), ac3);
      }
      const float s = fast_sigmoid(a + bias + (ac0 + ac1) + (ac2 + ac3));
      if (role == 0) {
        gv[h] = s;                     // z gate for C's epilogue
      } else {
        float rh = s * phv;            // r gate -> packed r*ph
        float nb = __shfl_xor(rh, 1, 64);
        if ((h & 1) == 0) rhp[h >> 1] = pkrtz(rh, nb);
      }
    }
    __syncthreads();   // B1: rhp + gv ready; ALL php reads complete

    if (role == 2) {
      // phase 2: full-K Uh dot over packed r*ph + epilogue, no part[] exchange, no B2
      const float4* vq = (const float4*)rhp;
      float c0 = 0.f, c1 = 0.f, c2 = 0.f, c3 = 0.f;
#pragma unroll
      for (int q = 0; q < 32; ++q) {
        float4 blk = vq[q];
        c0 = dot2f(u[4 * q + 0], f2h2(blk.x), c0);
        c1 = dot2f(u[4 * q + 1], f2h2(blk.y), c1);
        c2 = dot2f(u[4 * q + 2], f2h2(blk.z), c2);
        c3 = dot2f(u[4 * q + 3], f2h2(blk.w), c3);
      }
      const float c  = fast_tanh(a + bias + (c0 + c1) + (c2 + c3));
      const float g  = gv[h];
      const float hn = fmaf(g, phv, (1.f - g) * c);
      float nb = __shfl_xor(hn, 1, 64);   // DPP xor-1
      if ((h & 1) == 0) {                 // handoff store FIRST (children poll this)
        __hip_atomic_store(&HpkU[(size_t)i * (HID / 2) + (h >> 1)],
                           __builtin_bit_cast(unsigned, pkrtz(hn, nb)),
                           __ATOMIC_RELAXED, __HIP_MEMORY_SCOPE_AGENT);
      }
      H[(size_t)i * HID + h] = hn;        // fp32 row for leafmax (off critical path)
      if (inext < N_NODES) a = Aptr[(size_t)inext * HID + h];
    } else if (inext < N_NODES) {
      // Z/R: prefetch next A-row; Z pollers refill php overlapped with C's phase2
      a = Aptr[(size_t)inext * HID + h];
      if (tid < HID / 2) {
        const int pn = edge[2 * inext];   // parent, pn < inext
        unsigned v = __hip_atomic_load(&HpkU[(size_t)pn * (HID / 2) + tid],
                                       __ATOMIC_RELAXED, __HIP_MEMORY_SCOPE_AGENT);
        long spin = 0;
        while (v == POISON) {
          if (++spin > (1L << 22)) break; // escape hatch (should never trigger)
          v = __hip_atomic_load(&HpkU[(size_t)pn * (HID / 2) + tid],
                                __ATOMIC_RELAXED, __HIP_MEMORY_SCOPE_AGENT);
        }
        php[tid] = __builtin_bit_cast(half2_t, v);
      }
    }
    // loop -> B0 joins C's epilogue with Z's poll before any php/rhp/gv reuse
  }
}

// ---------------------------------------------------------------- leaf max partial (64 blocks x 32 leaves)
__global__ void leafmax_kernel(const float* __restrict__ H, const int* __restrict__ leafs,
                               float* __restrict__ partial) {
  int b = blockIdx.x;
  int h = threadIdx.x;
  float m = -INFINITY;
#pragma unroll 4
  for (int j = 0; j < N_LEAF / 64; ++j) {
    int node = leafs[b * (N_LEAF / 64) + j];
    m = fmaxf(m, H[(size_t)node * HID + h]);
  }
  partial[b * HID + h] = m;
}

// ---------------------------------------------------------------- final: reduce partials, W_out, softmax, loss
__global__ void final_kernel(const float* __restrict__ partial, const float* __restrict__ W_out,
                             const float* __restrict__ b_out, const float* __restrict__ y,
                             float* __restrict__ out) {
  int h = threadIdx.x;
  float m = -INFINITY;
#pragma unroll 8
  for (int b = 0; b < 64; ++b) m = fmaxf(m, partial[b * HID + h]);
  __shared__ float fs[HID];
  __shared__ float red[HID];
  __shared__ float logit[NCLASS];
  fs[h] = m;
  __syncthreads();
  for (int c = 0; c < NCLASS; ++c) {
    red[h] = W_out[c * HID + h] * fs[h];
    __syncthreads();
    for (int s = HID / 2; s > 0; s >>= 1) {
      if (h < s) red[h] += red[h + s];
      __syncthreads();
    }
    if (h == 0) logit[c] = red[0] + b_out[c];
    __syncthreads();
  }
  if (h == 0) {
    float mx = logit[0];
    for (int c = 1; c < NCLASS; ++c) mx = fmaxf(mx, logit[c]);
    float e[NCLASS], s = 0.f;
    for (int c = 0; c < NCLASS; ++c) { e[c] = expf(logit[c] - mx); s += e[c]; }
    float loss = 0.f;
    for (int c = 0; c < NCLASS; ++c) {
      float p = e[c] / s;
      out[c] = p;
      float d = y[c] - p;
      loss += d * d;
    }
    out[NCLASS] = loss;
  }
}

// ---------------------------------------------------------------- launch
extern "C" void kernel_launch(void* const* d_in, const int* in_sizes, int n_in,
                              void* d_out, int out_size, void* d_ws, size_t ws_size,
                              hipStream_t stream) {
  const int*   tree = (const int*)d_in[0];
  const int*   edge = (const int*)d_in[1];
  const int*   leaf = (const int*)d_in[2];
  const float* y    = (const float*)d_in[3];
  const float* E    = (const float*)d_in[4];
  const float* Wz   = (const float*)d_in[5];
  const float* Uz   = (const float*)d_in[6];
  const float* bz   = (const float*)d_in[7];
  const float* Wr   = (const float*)d_in[8];
  const float* Ur   = (const float*)d_in[9];
  const float* br   = (const float*)d_in[10];
  const float* Wh   = (const float*)d_in[11];
  const float* Uh   = (const float*)d_in[12];
  const float* bh   = (const float*)d_in[13];
  const float* Wout = (const float*)d_in[14];
  const float* bout = (const float*)d_in[15];
  float* out = (float*)d_out;

  char* base = (char*)d_ws;
  size_t b = 0;
  _Float16* ETh = (_Float16*)(base + b); b += (size_t)VOCAB * HID * 2;      // 25.7 MB
  b = (b + 255) & ~(size_t)255;
  half2_t* Upk = (half2_t*)(base + b); b += (size_t)6 * 4 * 8192 * 4;       // U(3) + W(3) packed
  half2_t* Hpk = (half2_t*)(base + b); b += (size_t)N_NODES * (HID / 2) * 4;
  float* Az  = (float*)(base + b); b += (size_t)N_NODES * HID * 4;
  float* Ar  = (float*)(base + b); b += (size_t)N_NODES * HID * 4;
  float* Ah  = (float*)(base + b); b += (size_t)N_NODES * HID * 4;
  float* H   = (float*)(base + b); b += (size_t)N_NODES * HID * 4;
  float* partial = (float*)(base + b); b += (size_t)64 * HID * 4;

  poison_hpk_kernel<<<(N_NODES * (HID / 2) + 255) / 256, 256, 0, stream>>>((unsigned*)Hpk);
  transpose_f16_kernel<<<dim3((VOCAB + 31) / 32, HID / 32), dim3(32, 8), 0, stream>>>(E, ETh, HID, VOCAB);
  pack_u_kernel<<<24, 256, 0, stream>>>(Uz, Ur, Uh, Wz, Wr, Wh, Upk);
  gather_gemv_kernel<<<N_NODES / 4, 256, 0, stream>>>(tree, (const half2_t*)ETh, Upk,
                                                      Az, Ar, Ah, H, Hpk);
  rnn_kernel<<<RNN_BLOCKS, 768, 0, stream>>>(Az, Ar, Ah, Upk, bz, br, bh, edge, H, (unsigned*)Hpk);
  leafmax_kernel<<<64, HID, 0, stream>>>(H, leaf, partial);
  final_kernel<<<1, HID, 0, stream>>>(partial, Wout, bout, y, out);
}